// Round 10
// baseline (570.959 us; speedup 1.0000x reference)
//
#include <hip/hip_runtime.h>
#include <hip/hip_bf16.h>

#define IN_F   2048
#define OUT_F  2048
#define NG     8
#define BATCH  4096
#define KDIM   (IN_F * (NG + 1))   // 18432
#define BK     64
#define NT     (KDIM / BK)         // 288
#define BM     256
#define BN     128
#define ABUF   32768               // A tile bytes: 256 x 64 x 2

typedef short bf16x8 __attribute__((ext_vector_type(8)));
typedef float f32x4  __attribute__((ext_vector_type(4)));
typedef __attribute__((address_space(3))) unsigned char       lds_u8;
typedef const __attribute__((address_space(1))) unsigned char glb_u8;

__device__ __forceinline__ float sigmoidf_(float v) {
    return 1.0f / (1.0f + __expf(-v));
}

// round-to-nearest-even f32 -> bf16 (as ushort)
__device__ __forceinline__ unsigned short f2bf(float f) {
    unsigned int u = __builtin_bit_cast(unsigned int, f);
    u = (u + 0x7fffu + ((u >> 16) & 1u)) >> 16;
    return (unsigned short)u;
}

// ---------------------------------------------------------------------------
// Kernel 1: activation prep (unchanged).  A'[b][k] bf16 flat, K-contiguous.
// ---------------------------------------------------------------------------
__global__ __launch_bounds__(256) void act_kernel(
    const float* __restrict__ x, const float* __restrict__ fi,
    const float* __restrict__ gr, unsigned short* __restrict__ Abf)
{
    const int base = blockIdx.x * 1024;
    const int tid  = threadIdx.x;
    const int b    = base >> 11;                    // uniform per block
    const float4 g0 = *(const float4*)gr;
    const float4 g1 = *(const float4*)(gr + 4);
    unsigned short* rowp = Abf + (size_t)b * KDIM;

#pragma unroll
    for (int e = 0; e < 4; ++e) {
        const int idx = base + tid + e * 256;
        const int i   = idx & (IN_F - 1);
        const float s  = sigmoidf_(fi[i]);
        const float xw = x[idx] * s;
        const float ex = __expf(2.0f * xw);
        const float xn = (ex - 1.0f) / (ex + 1.0f);

        float ev[NG];
        float d;
        d = xn - g0.x; ev[0] = __expf(-2.0f * d * d);
        d = xn - g0.y; ev[1] = __expf(-2.0f * d * d);
        d = xn - g0.z; ev[2] = __expf(-2.0f * d * d);
        d = xn - g0.w; ev[3] = __expf(-2.0f * d * d);
        d = xn - g1.x; ev[4] = __expf(-2.0f * d * d);
        d = xn - g1.y; ev[5] = __expf(-2.0f * d * d);
        d = xn - g1.z; ev[6] = __expf(-2.0f * d * d);
        d = xn - g1.w; ev[7] = __expf(-2.0f * d * d);
        float denom = ((ev[0] + ev[1]) + (ev[2] + ev[3])) +
                      ((ev[4] + ev[5]) + (ev[6] + ev[7]));
        const float rinv = 1.0f / fmaxf(denom, 1e-12f);

        union { unsigned short us[8]; int4 v; } pk;
#pragma unroll
        for (int g = 0; g < NG; ++g) pk.us[g] = f2bf(ev[g] * rinv);
        *(int4*)(rowp + i * NG) = pk.v;
        rowp[IN_F * NG + i] = f2bf(xw);
    }
}

// ---------------------------------------------------------------------------
// Kernel 2: weight prep -> BLOCKED layout for direct L2 B-gather.
//   W''[bn][t][kq][row][8] (shorts): chunk = ((bn*288+t)*8+kq)*1024 + row*8
//   spline (o,i): t=i>>3, kq=i&7, row=o&127, elem=g
//   base   (o,i): t=256+(i>>6), kq=(i>>3)&7, row=o&127, elem=i&7
// Block = 128 o x 16 i: reads coalesced; each 2KB output plane fully
// written by one block (L2 write-combining keeps HBM writes ~=75MB).
// ---------------------------------------------------------------------------
__global__ __launch_bounds__(256) void wprep_kernel(
    const float* __restrict__ bw, const float* __restrict__ sw,
    const float* __restrict__ ag, unsigned short* __restrict__ Wpp)
{
    const int bn = blockIdx.x >> 7;          // 0..15
    const int it = blockIdx.x & 127;         // 0..127
    const int i0 = it * 16;
    const int tid = threadIdx.x;
    unsigned short* base = Wpp + (size_t)bn * 288 * 8192;

#pragma unroll
    for (int e = 0; e < 8; ++e) {
        const int idx = e * 256 + tid;       // 0..2047
        const int o   = idx >> 4;            // 0..127 (row)
        const int i   = i0 + (idx & 15);
        const int go  = bn * 128 + o;        // global o
        const float gate = sigmoidf_(ag[go]);
        const float og   = 1.0f - gate;

        const size_t srow = ((size_t)go * IN_F + i) * NG;
        const float4 s0 = *(const float4*)(sw + srow);
        const float4 s1 = *(const float4*)(sw + srow + 4);
        union { unsigned short us[8]; int4 v; } pk;
        pk.us[0] = f2bf(gate * s0.x); pk.us[1] = f2bf(gate * s0.y);
        pk.us[2] = f2bf(gate * s0.z); pk.us[3] = f2bf(gate * s0.w);
        pk.us[4] = f2bf(gate * s1.x); pk.us[5] = f2bf(gate * s1.y);
        pk.us[6] = f2bf(gate * s1.z); pk.us[7] = f2bf(gate * s1.w);
        *(int4*)(base + ((size_t)(i >> 3) * 8 + (i & 7)) * 1024 + o * 8) = pk.v;

        base[((size_t)(256 + (i >> 6)) * 8 + ((i >> 3) & 7)) * 1024 + o * 8 + (i & 7)]
            = f2bf(og * bw[(size_t)go * IN_F + i]);
    }
}

// ---------------------------------------------------------------------------
// Kernel 3: bf16 GEMM.  C = A'[4096][K] * W''^T, K=18432.
// BM=256 BN=128 BK=64, 8 waves = 2M x 2N x 2Ksub (per-wave 128x64).
// A: LDS (3 x 32KB bufs, XOR-swizzled, global_load_lds) — 64KB reads +
// 32KB writes per tile (< MFMA 1241cyc -> MFMA-critical).
// B: global->VGPR direct from blocked W'' (L2-resident), prefetched 1 tile
// ahead.  Single barrier/tile, counted vmcnt(8), T5 setprio. Split-K epilogue.
// ---------------------------------------------------------------------------
#define MFMA(d, a, b) d = __builtin_amdgcn_mfma_f32_16x16x32_bf16(a, b, d, 0, 0, 0)

#define LDA(m) (*(const bf16x8*)(lds + curBase + oA##m))

#define GLA(j) __builtin_amdgcn_global_load_lds((glb_u8*)(aS##j + ko), \
                   (lds_u8*)(lds + stBase + aO##j), 16, 0, 0)

__global__ __launch_bounds__(512, 2) void gemm_kernel(
    const unsigned short* __restrict__ A, const unsigned short* __restrict__ B,
    const float* __restrict__ bb, const float* __restrict__ ag,
    float* __restrict__ C)
{
    __shared__ __align__(16) unsigned char lds[131072];  // 96KB staging + 128KB redn

    const int tid = threadIdx.x;
    const int bid = blockIdx.x;
    const int swz = ((bid & 7) << 5) + (bid >> 3);       // bijective XCD swizzle
    const int bm = swz >> 4, bn = swz & 15;

    const int lane = tid & 63, wid = tid >> 6;
    const int ks = wid & 1, wn = (wid >> 1) & 1, wm = wid >> 2;
    const int fr = lane & 15, kg = lane >> 4;
    const int kq = 4 * ks + kg;

    // ---- A staging: pre-swizzled global source, linear LDS dest
#define MKSA(j)                                                         \
    const int eA##j = tid + (j) * 512;                                  \
    const int rA_##j = eA##j >> 3, cA_##j = (eA##j & 7) ^ (rA_##j & 7); \
    const unsigned short* aS##j = A + (size_t)(bm * BM + rA_##j) * KDIM + cA_##j * 8; \
    const int aO##j = eA##j * 16;
    MKSA(0) MKSA(1) MKSA(2) MKSA(3)

    // ---- A ds_read offsets (R2-verified 0-conflict XOR mapping)
#define MKOA(m)                                                \
    const int rAm##m = wm * 128 + (m) * 16 + fr;               \
    const int oA##m = rAm##m * 128 + ((kq ^ (rAm##m & 7)) << 4);
    MKOA(0) MKOA(1) MKOA(2) MKOA(3) MKOA(4) MKOA(5) MKOA(6) MKOA(7)

    // ---- B direct-gather base: W'' chunk = ((bn*288+t)*8+kq)*1024 + row*8
    const unsigned short* Bw = B + (size_t)bn * 288 * 8192 + kq * 1024
                                 + (wn * 64 + fr) * 8;
#define LDBG(t_, n_) (*(const bf16x8*)(Bw + (size_t)(t_) * 8192 + (n_) * 128))

    f32x4 acc[8][4] = {};

    // ---- prologue: stage A(0),A(1); load B(0) to regs
    {
        const int stBase = 0; const long ko = 0;
        GLA(0); GLA(1); GLA(2); GLA(3);
    }
    {
        const int stBase = ABUF; const long ko = BK;
        GLA(0); GLA(1); GLA(2); GLA(3);
    }
    bf16x8 cb0 = LDBG(0, 0), cb1 = LDBG(0, 1), cb2 = LDBG(0, 2), cb3 = LDBG(0, 3);
    asm volatile("s_waitcnt vmcnt(8)" ::: "memory");   // A(0) landed
    __builtin_amdgcn_s_barrier();
    __builtin_amdgcn_sched_barrier(0);

    int curBase = 0;
    for (int t = 0; t < NT; ++t) {
        const int stBase = (curBase == 0) ? 2 * ABUF
                         : (curBase == ABUF) ? 0 : ABUF;
        const bool doB  = (t + 1) < NT;
        const bool doSt = (t + 2) < NT;
        const long ko = (long)(t + 2) * BK;

        // prefetch B(t+1) into regs (L2 latency hides under MFMA)
        bf16x8 nb0, nb1, nb2, nb3;
        if (doB) { nb0 = LDBG(t + 1, 0); nb1 = LDBG(t + 1, 1);
                   nb2 = LDBG(t + 1, 2); nb3 = LDBG(t + 1, 3); }
        if (doSt) { GLA(0); GLA(1); GLA(2); GLA(3); }

        // A frags from LDS (compiler emits counted lgkmcnt per cluster)
        bf16x8 va0 = LDA(0), va1 = LDA(1), va2 = LDA(2), va3 = LDA(3);
        bf16x8 va4 = LDA(4), va5 = LDA(5), va6 = LDA(6), va7 = LDA(7);

        __builtin_amdgcn_s_setprio(1);
        MFMA(acc[0][0], va0, cb0); MFMA(acc[0][1], va0, cb1);
        MFMA(acc[0][2], va0, cb2); MFMA(acc[0][3], va0, cb3);
        MFMA(acc[1][0], va1, cb0); MFMA(acc[1][1], va1, cb1);
        MFMA(acc[1][2], va1, cb2); MFMA(acc[1][3], va1, cb3);
        MFMA(acc[2][0], va2, cb0); MFMA(acc[2][1], va2, cb1);
        MFMA(acc[2][2], va2, cb2); MFMA(acc[2][3], va2, cb3);
        MFMA(acc[3][0], va3, cb0); MFMA(acc[3][1], va3, cb1);
        MFMA(acc[3][2], va3, cb2); MFMA(acc[3][3], va3, cb3);
        MFMA(acc[4][0], va4, cb0); MFMA(acc[4][1], va4, cb1);
        MFMA(acc[4][2], va4, cb2); MFMA(acc[4][3], va4, cb3);
        MFMA(acc[5][0], va5, cb0); MFMA(acc[5][1], va5, cb1);
        MFMA(acc[5][2], va5, cb2); MFMA(acc[5][3], va5, cb3);
        MFMA(acc[6][0], va6, cb0); MFMA(acc[6][1], va6, cb1);
        MFMA(acc[6][2], va6, cb2); MFMA(acc[6][3], va6, cb3);
        MFMA(acc[7][0], va7, cb0); MFMA(acc[7][1], va7, cb1);
        MFMA(acc[7][2], va7, cb2); MFMA(acc[7][3], va7, cb3);
        __builtin_amdgcn_s_setprio(0);

        // barrier: A(t+1) landed (8 younger: 4 nb + 4 A-stage)
        __builtin_amdgcn_sched_barrier(0);
        if (doSt)      { asm volatile("s_waitcnt vmcnt(8)" ::: "memory"); }
        else if (doB)  { asm volatile("s_waitcnt vmcnt(4)" ::: "memory"); }
        else           { asm volatile("s_waitcnt vmcnt(0)" ::: "memory"); }
        __builtin_amdgcn_s_barrier();
        __builtin_amdgcn_sched_barrier(0);

        if (doB) { cb0 = nb0; cb1 = nb1; cb2 = nb2; cb3 = nb3; }
        curBase = (curBase == 2 * ABUF) ? 0 : (curBase + ABUF);
    }

    // ---- cross-wave K-reduction through LDS (staging dead after last barrier)
    const int slot = wm * 2 + wn;
    if (ks == 1) {
#pragma unroll
        for (int m = 0; m < 8; ++m)
#pragma unroll
            for (int n = 0; n < 4; ++n)
                *(f32x4*)(lds + slot * 32768 + (m * 4 + n) * 1024 + lane * 16)
                    = acc[m][n];
    }
    __syncthreads();
    if (ks == 0) {
        const int colb = bn * BN + wn * 64;
        const int rowb = bm * BM + wm * 128;
#pragma unroll
        for (int n = 0; n < 4; ++n) {
            const int col = colb + n * 16 + fr;
            const float gate = sigmoidf_(ag[col]);
            const float bias = (1.0f - gate) * bb[col];
#pragma unroll
            for (int m = 0; m < 8; ++m) {
                const f32x4 part =
                    *(const f32x4*)(lds + slot * 32768 + (m * 4 + n) * 1024 + lane * 16);
                const int r0 = rowb + m * 16 + kg * 4;
#pragma unroll
                for (int j = 0; j < 4; ++j)
                    C[(size_t)(r0 + j) * OUT_F + col] = acc[m][n][j] + part[j] + bias;
            }
        }
    }
}

// ---------------------------------------------------------------------------
extern "C" void kernel_launch(void* const* d_in, const int* in_sizes, int n_in,
                              void* d_out, int out_size, void* d_ws, size_t ws_size,
                              hipStream_t stream)
{
    const float* x  = (const float*)d_in[0];   // [4096,2048]
    const float* bw = (const float*)d_in[1];   // [2048,2048]
    const float* bb = (const float*)d_in[2];   // [2048]
    const float* sw = (const float*)d_in[3];   // [2048,2048,8]
    const float* gr = (const float*)d_in[4];   // [8]
    const float* ag = (const float*)d_in[5];   // [2048]
    const float* fi = (const float*)d_in[6];   // [2048]
    float* out = (float*)d_out;                // [4096,2048] f32

    unsigned short* Abf = (unsigned short*)d_ws;             // [4096][18432] bf16
    unsigned short* Wpp = Abf + (size_t)BATCH * KDIM;        // blocked W'' (75MB)

    const size_t need = ((size_t)BATCH + OUT_F) * KDIM * sizeof(unsigned short);
    if (ws_size < need) return;

    act_kernel<<<BATCH * IN_F / 1024, 256, 0, stream>>>(x, fi, gr, Abf);
    wprep_kernel<<<16 * 128, 256, 0, stream>>>(bw, sw, ag, Wpp);
    gemm_kernel<<<(BATCH / BM) * (OUT_F / BN), 512, 0, stream>>>(Abf, Wpp, bb, ag, out);
}